// Round 8
// baseline (232.887 us; speedup 1.0000x reference)
//
#include <hip/hip_runtime.h>

#define D 128
#define BW_LOG 6          // 64 nodes per bucket
#define BWID 64
#define CAP 4096          // max edges per bucket in LDS (mean ~2048, max ~2350)
#define CHUNK 4096        // edges per partition block (391 blocks -> occupancy)
#define NB_MAX 1024       // supports N <= 65536 (also required by 16-bit src packing)

typedef unsigned short u16;
typedef unsigned int u32;
typedef __attribute__((ext_vector_type(8))) short bf16x8;      // 8 bf16 (4 VGPRs)
typedef __attribute__((ext_vector_type(8))) unsigned short u16x8;
typedef __attribute__((ext_vector_type(4))) float f32x4;

__device__ __forceinline__ float bf2f(u16 h) { return __uint_as_float(((u32)h) << 16); }
__device__ __forceinline__ u16 f2bf(float f) {
    u32 u = __float_as_uint(f);
    u32 r = (u + 0x7fffu + ((u >> 16) & 1u)) >> 16;   // RNE
    return (u16)r;
}

// ---------- dtype conversion ----------

__global__ __launch_bounds__(256)
void cvt_x_kernel(const float* __restrict__ x, u16* __restrict__ xb, int n4) {
    int i = blockIdx.x * 256 + threadIdx.x;
    if (i < n4) {
        float4 v = ((const float4*)x)[i];
        ushort4 o;
        o.x = f2bf(v.x); o.y = f2bf(v.y); o.z = f2bf(v.z); o.w = f2bf(v.w);
        ((ushort4*)xb)[i] = o;
    }
}

// both layers' wcat in one launch: blocks 0..127 -> wc1 row n, 128..255 -> wc2 row n-128
__global__ __launch_bounds__(256)
void cvt_w_kernel(const float* __restrict__ W1l, const float* __restrict__ W1r,
                  const float* __restrict__ W2l, const float* __restrict__ W2r,
                  u16* __restrict__ wc1, u16* __restrict__ wc2) {
    int b = blockIdx.x, k = threadIdx.x;
    int n = b & 127;
    const float* Wl = (b < 128) ? W1l : W2l;
    const float* Wr = (b < 128) ? W1r : W2r;
    u16* wcat = (b < 128) ? wc1 : wc2;
    float v = (k < 128) ? Wl[n * 128 + k] : Wr[n * 128 + k - 128];
    wcat[n * 256 + k] = f2bf(v);
}

// ---------- CSR build via deterministic two-pass privatized counting sort ----------

__global__ __launch_bounds__(256)
void part_hist_kernel(const int* __restrict__ dst, int* __restrict__ gh,
                      int E, int nb, int nblk) {
    __shared__ int h[NB_MAX];
    int b = blockIdx.x;
    for (int i = threadIdx.x; i < nb; i += 256) h[i] = 0;
    __syncthreads();
    int lo = b * CHUNK, hi = min(lo + CHUNK, E);
    for (int i = lo + threadIdx.x; i < hi; i += 256) atomicAdd(&h[dst[i] >> BW_LOG], 1);
    __syncthreads();
    for (int i = threadIdx.x; i < nb; i += 256) gh[(size_t)i * nblk + b] = h[i];
}

__global__ __launch_bounds__(64)
void part_scan1_kernel(int* __restrict__ gh, int* __restrict__ btot, int nblk) {
    int k = blockIdx.x;
    int t = threadIdx.x;
    int* row = gh + (size_t)k * nblk;
    int chunk = (nblk + 63) >> 6;
    int lo = t * chunk, hi = min(lo + chunk, nblk);
    int s = 0;
    for (int i = lo; i < hi; ++i) s += row[i];
    int incl = s;
#pragma unroll
    for (int d2 = 1; d2 < 64; d2 <<= 1) { int u = __shfl_up(incl, d2, 64); if (t >= d2) incl += u; }
    int excl = incl - s;
    for (int i = lo; i < hi; ++i) { int c = row[i]; row[i] = excl; excl += c; }
    if (t == 63) btot[k] = incl;
}

__global__ __launch_bounds__(1024)
void part_scan2_kernel(const int* __restrict__ btot, int* __restrict__ bbase,
                       int nb, int* __restrict__ offN) {
    __shared__ int ws[16];
    int t = threadIdx.x, lane = t & 63, wid = t >> 6;
    int v = (t < nb) ? btot[t] : 0;
    int incl = v;
#pragma unroll
    for (int d2 = 1; d2 < 64; d2 <<= 1) { int u = __shfl_up(incl, d2, 64); if (lane >= d2) incl += u; }
    if (lane == 63) ws[wid] = incl;
    __syncthreads();
    if (wid == 0) {
        int w = (lane < 16) ? ws[lane] : 0;
#pragma unroll
        for (int d2 = 1; d2 < 16; d2 <<= 1) { int u = __shfl_up(w, d2, 64); if (lane >= d2) w += u; }
        if (lane < 16) ws[lane] = w;
    }
    __syncthreads();
    int base = wid ? ws[wid - 1] : 0;
    int excl = base + incl - v;
    if (t < nb) bbase[t] = excl;
    if (t == nb - 1) { bbase[nb] = excl + v; *offN = excl + v; }
}

// record = (dst_local << 16) | src   (src < 65536)
__global__ __launch_bounds__(256)
void part_scatter_kernel(const int* __restrict__ src, const int* __restrict__ dst,
                         const int* __restrict__ gh, const int* __restrict__ bbase,
                         u32* __restrict__ ebuf, int E, int nb, int nblk) {
    __shared__ int cur[NB_MAX];
    int b = blockIdx.x;
    for (int i = threadIdx.x; i < nb; i += 256)
        cur[i] = bbase[i] + gh[(size_t)i * nblk + b];
    __syncthreads();
    int lo = b * CHUNK, hi = min(lo + CHUNK, E);
    for (int i = lo + threadIdx.x; i < hi; i += 256) {
        int d = dst[i];
        int p = atomicAdd(&cur[d >> BW_LOG], 1);
        ebuf[p] = ((u32)(d & (BWID - 1)) << 16) | (u32)src[i];
    }
}

__global__ __launch_bounds__(256)
void bucket_sort_kernel(u32* __restrict__ ebuf, const int* __restrict__ bbase,
                        int* __restrict__ off, int n_nodes) {
    __shared__ u32 in_s[CAP];
    __shared__ u16 out_s[CAP];
    __shared__ int hist[BWID], cur[BWID];
    int b = blockIdx.x;
    int base = bbase[b];
    int n_b = bbase[b + 1] - base;
    int t = threadIdx.x;
    if (t < BWID) hist[t] = 0;
    for (int i = t; i < n_b && i < CAP; i += 256) in_s[i] = ebuf[base + i];
    __syncthreads();
    for (int i = t; i < n_b && i < CAP; i += 256) atomicAdd(&hist[in_s[i] >> 16], 1);
    __syncthreads();
    if (t < BWID) {
        int s = hist[t];
        int incl = s;
#pragma unroll
        for (int d2 = 1; d2 < 64; d2 <<= 1) { int u = __shfl_up(incl, d2, 64); if (t >= d2) incl += u; }
        int excl = incl - s;
        cur[t] = excl;
        int node = (b << BW_LOG) + t;
        if (node < n_nodes) off[node] = base + excl;
    }
    __syncthreads();
    for (int i = t; i < n_b && i < CAP; i += 256) {
        u32 v = in_s[i];
        int p = atomicAdd(&cur[v >> 16], 1);
        if (p < CAP) out_s[p] = (u16)(v & 0xffffu);
    }
    __syncthreads();
    for (int i = t; i < n_b && i < CAP; i += 256) ebuf[base + i] = (u32)out_s[i];
}

// ---------- mean aggregation over bf16 rows ----------
// 16 lanes per node (u16x8/lane covers D=128), edge loop unrolled x8, fp32 acc, bf16 out.
// 16 nodes per 256-thread block -> 3125 blocks, high occupancy for latency hiding.

__global__ __launch_bounds__(256)
void aggregate_bf16_kernel(const u16* __restrict__ xb, const int* __restrict__ off,
                           const u32* __restrict__ eidx, u16* __restrict__ meanb,
                           int n_nodes) {
    int node = blockIdx.x * 16 + (threadIdx.x >> 4);
    int lane = threadIdx.x & 15;
    if (node >= n_nodes) return;
    int beg = off[node], end = off[node + 1];
    int c = lane * 8;

    float acc[8] = {};
    int e = beg;
    for (; e + 8 <= end; e += 8) {
        u16x8 v0 = *(const u16x8*)&xb[(size_t)eidx[e + 0] * D + c];
        u16x8 v1 = *(const u16x8*)&xb[(size_t)eidx[e + 1] * D + c];
        u16x8 v2 = *(const u16x8*)&xb[(size_t)eidx[e + 2] * D + c];
        u16x8 v3 = *(const u16x8*)&xb[(size_t)eidx[e + 3] * D + c];
        u16x8 v4 = *(const u16x8*)&xb[(size_t)eidx[e + 4] * D + c];
        u16x8 v5 = *(const u16x8*)&xb[(size_t)eidx[e + 5] * D + c];
        u16x8 v6 = *(const u16x8*)&xb[(size_t)eidx[e + 6] * D + c];
        u16x8 v7 = *(const u16x8*)&xb[(size_t)eidx[e + 7] * D + c];
#pragma unroll
        for (int j = 0; j < 8; ++j)
            acc[j] += bf2f(v0[j]) + bf2f(v1[j]) + bf2f(v2[j]) + bf2f(v3[j])
                    + bf2f(v4[j]) + bf2f(v5[j]) + bf2f(v6[j]) + bf2f(v7[j]);
    }
    for (; e < end; ++e) {
        u16x8 v = *(const u16x8*)&xb[(size_t)eidx[e] * D + c];
#pragma unroll
        for (int j = 0; j < 8; ++j) acc[j] += bf2f(v[j]);
    }

    int deg = end - beg;
    float inv = 1.f / (float)(deg > 0 ? deg : 1);
    u16x8 o;
#pragma unroll
    for (int j = 0; j < 8; ++j) o[j] = f2bf(acc[j] * inv);
    *(u16x8*)&meanb[(size_t)node * D + c] = o;
}

// ---------- linear via MFMA with LDS-staged W ----------
// out = relu([mean||self] @ Wcat^T + b). Block = 64 rows (4 waves x 16-row tiles).
// Wcat (128x256 bf16) staged in LDS in two 32KB k-halves.
// mfma_f32_16x16x32_bf16: A row=l&15, k=(l>>4)*8+j ; C/D col=l&15, row=(l>>4)*4+reg.

template<bool OUT_BF16>
__global__ __launch_bounds__(256)
void linear_mfma_kernel(const u16* __restrict__ Amean, const u16* __restrict__ Aself,
                        const u16* __restrict__ Wc, const float* __restrict__ bias,
                        void* __restrict__ outp, int N) {
    __shared__ u16 ws[128][136];   // 34816 B

    int t = threadIdx.x;
    int l = t & 63;
    int wv = t >> 6;
    int m0 = blockIdx.x * 64 + wv * 16;
    int lr = l & 15;
    int kg = (l >> 4) * 8;
    int rowA = m0 + lr;
    int rc = rowA < N ? rowA : N - 1;
    const u16* r1 = Amean + (size_t)rc * D;
    const u16* r2 = Aself + (size_t)rc * D;

    bf16x8 a[8];
#pragma unroll
    for (int kt = 0; kt < 4; ++kt) {
        a[kt]     = *(const bf16x8*)(r1 + kt * 32 + kg);   // k 0..127  (mean)
        a[kt + 4] = *(const bf16x8*)(r2 + kt * 32 + kg);   // k 128..255 (self)
    }

    f32x4 acc[8];
#pragma unroll
    for (int nt = 0; nt < 8; ++nt) acc[nt] = (f32x4){0.f, 0.f, 0.f, 0.f};

    for (int half = 0; half < 2; ++half) {
        if (half) __syncthreads();         // all reads of previous half done
        // stage 128x128 bf16 k-half of Wcat: 2048 x 16B, 8 per thread
        for (int i = t; i < 2048; i += 256) {
            int n = i >> 4, kq = i & 15;
            *(u16x8*)&ws[n][kq * 8] = *(const u16x8*)&Wc[(size_t)n * 256 + half * 128 + kq * 8];
        }
        __syncthreads();

#pragma unroll
        for (int nt = 0; nt < 8; ++nt) {
            bf16x8 b0 = *(const bf16x8*)&ws[nt * 16 + lr][0 * 32 + kg];
            bf16x8 b1 = *(const bf16x8*)&ws[nt * 16 + lr][1 * 32 + kg];
            bf16x8 b2 = *(const bf16x8*)&ws[nt * 16 + lr][2 * 32 + kg];
            bf16x8 b3 = *(const bf16x8*)&ws[nt * 16 + lr][3 * 32 + kg];
            acc[nt] = __builtin_amdgcn_mfma_f32_16x16x32_bf16(a[half * 4 + 0], b0, acc[nt], 0, 0, 0);
            acc[nt] = __builtin_amdgcn_mfma_f32_16x16x32_bf16(a[half * 4 + 1], b1, acc[nt], 0, 0, 0);
            acc[nt] = __builtin_amdgcn_mfma_f32_16x16x32_bf16(a[half * 4 + 2], b2, acc[nt], 0, 0, 0);
            acc[nt] = __builtin_amdgcn_mfma_f32_16x16x32_bf16(a[half * 4 + 3], b3, acc[nt], 0, 0, 0);
        }
    }

#pragma unroll
    for (int nt = 0; nt < 8; ++nt) {
        int col = nt * 16 + lr;
        float bb = bias[col];
#pragma unroll
        for (int j = 0; j < 4; ++j) {
            int r = m0 + (l >> 4) * 4 + j;
            if (r < N) {
                float v = fmaxf(acc[nt][j] + bb, 0.f);
                if (OUT_BF16) ((u16*)outp)[(size_t)r * D + col] = f2bf(v);
                else          ((float*)outp)[(size_t)r * D + col] = v;
            }
        }
    }
}

extern "C" void kernel_launch(void* const* d_in, const int* in_sizes, int n_in,
                              void* d_out, int out_size, void* d_ws, size_t ws_size,
                              hipStream_t stream) {
    const float* x   = (const float*)d_in[0];
    const int*   ei  = (const int*)d_in[1];
    const float* W1l = (const float*)d_in[2];
    const float* W1r = (const float*)d_in[3];
    const float* b1  = (const float*)d_in[4];
    const float* W2l = (const float*)d_in[5];
    const float* W2r = (const float*)d_in[6];
    const float* b2  = (const float*)d_in[7];
    float* out = (float*)d_out;

    const int N = in_sizes[0] / D;
    const int E = in_sizes[1] / 2;
    const int* src = ei;
    const int* dst = ei + E;
    const int NB = (N + BWID - 1) >> BW_LOG;       // 782 for N=50000 (<= NB_MAX)
    const int NBLK = (E + CHUNK - 1) / CHUNK;      // 391 for E=1.6M

    // workspace layout, 64B-aligned blocks
    char* wp_ = (char*)d_ws;
    auto alloc = [&](size_t bytes) { char* p = wp_; wp_ += (bytes + 63) & ~(size_t)63; return p; };
    int* off_p   = (int*)alloc((size_t)(N + 1) * 4);
    int* bbase_p = (int*)alloc((size_t)(NB + 1) * 4);
    int* btot_p  = (int*)alloc((size_t)NB * 4);
    int* gh_p    = (int*)alloc((size_t)NB * NBLK * 4);
    u32* ebuf_p  = (u32*)alloc((size_t)E * 4);
    u16* xb      = (u16*)alloc((size_t)N * D * 2);
    u16* meanb   = (u16*)alloc((size_t)N * D * 2);
    u16* h1b     = (u16*)alloc((size_t)N * D * 2);
    u16* wc1     = (u16*)alloc((size_t)128 * 256 * 2);
    u16* wc2     = (u16*)alloc((size_t)128 * 256 * 2);

    // conversions
    cvt_x_kernel<<<(N * D / 4 + 255) / 256, 256, 0, stream>>>(x, xb, N * D / 4);
    cvt_w_kernel<<<256, 256, 0, stream>>>(W1l, W1r, W2l, W2r, wc1, wc2);

    // CSR build
    part_hist_kernel<<<NBLK, 256, 0, stream>>>(dst, gh_p, E, NB, NBLK);
    part_scan1_kernel<<<NB, 64, 0, stream>>>(gh_p, btot_p, NBLK);
    part_scan2_kernel<<<1, 1024, 0, stream>>>(btot_p, bbase_p, NB, off_p + N);
    part_scatter_kernel<<<NBLK, 256, 0, stream>>>(src, dst, gh_p, bbase_p, ebuf_p, E, NB, NBLK);
    bucket_sort_kernel<<<NB, 256, 0, stream>>>(ebuf_p, bbase_p, off_p, N);

    // layer 1
    aggregate_bf16_kernel<<<(N + 15) / 16, 256, 0, stream>>>(xb, off_p, ebuf_p, meanb, N);
    linear_mfma_kernel<true><<<(N + 63) / 64, 256, 0, stream>>>(meanb, xb, wc1, b1, h1b, N);

    // layer 2
    aggregate_bf16_kernel<<<(N + 15) / 16, 256, 0, stream>>>(h1b, off_p, ebuf_p, meanb, N);
    linear_mfma_kernel<false><<<(N + 63) / 64, 256, 0, stream>>>(meanb, h1b, wc2, b2, out, N);
}

// Round 9
// 228.653 us; speedup vs baseline: 1.0185x; 1.0185x over previous
//
#include <hip/hip_runtime.h>

#define D 128
#define BW_LOG 6          // 64 nodes per bucket
#define BWID 64
#define CAP 4096          // max edges per bucket in LDS (mean ~2048, max ~2350)
#define CHUNK 4096        // edges per partition block (391 blocks -> occupancy)
#define NB_MAX 1024       // supports N <= 65536 (also required by 16-bit src packing)

typedef unsigned short u16;
typedef unsigned int u32;
typedef __attribute__((ext_vector_type(8))) short bf16x8;      // 8 bf16 (4 VGPRs)
typedef __attribute__((ext_vector_type(8))) unsigned short u16x8;
typedef __attribute__((ext_vector_type(4))) float f32x4;

__device__ __forceinline__ float bf2f(u16 h) { return __uint_as_float(((u32)h) << 16); }
__device__ __forceinline__ u16 f2bf(float f) {
    u32 u = __float_as_uint(f);
    u32 r = (u + 0x7fffu + ((u >> 16) & 1u)) >> 16;   // RNE
    return (u16)r;
}

// ---------- dtype conversion ----------

__global__ __launch_bounds__(256)
void cvt_x_kernel(const float* __restrict__ x, u16* __restrict__ xb, int n4) {
    int i = blockIdx.x * 256 + threadIdx.x;
    if (i < n4) {
        float4 v = ((const float4*)x)[i];
        ushort4 o;
        o.x = f2bf(v.x); o.y = f2bf(v.y); o.z = f2bf(v.z); o.w = f2bf(v.w);
        ((ushort4*)xb)[i] = o;
    }
}

// both layers' wcat in one launch: blocks 0..127 -> wc1 row n, 128..255 -> wc2 row n-128
__global__ __launch_bounds__(256)
void cvt_w_kernel(const float* __restrict__ W1l, const float* __restrict__ W1r,
                  const float* __restrict__ W2l, const float* __restrict__ W2r,
                  u16* __restrict__ wc1, u16* __restrict__ wc2) {
    int b = blockIdx.x, k = threadIdx.x;
    int n = b & 127;
    const float* Wl = (b < 128) ? W1l : W2l;
    const float* Wr = (b < 128) ? W1r : W2r;
    u16* wcat = (b < 128) ? wc1 : wc2;
    float v = (k < 128) ? Wl[n * 128 + k] : Wr[n * 128 + k - 128];
    wcat[n * 256 + k] = f2bf(v);
}

// ---------- CSR build via deterministic two-pass privatized counting sort ----------

__global__ __launch_bounds__(256)
void part_hist_kernel(const int* __restrict__ dst, int* __restrict__ gh,
                      int E, int nb, int nblk) {
    __shared__ int h[NB_MAX];
    int b = blockIdx.x;
    for (int i = threadIdx.x; i < nb; i += 256) h[i] = 0;
    __syncthreads();
    int lo = b * CHUNK, hi = min(lo + CHUNK, E);
    for (int i = lo + threadIdx.x; i < hi; i += 256) atomicAdd(&h[dst[i] >> BW_LOG], 1);
    __syncthreads();
    for (int i = threadIdx.x; i < nb; i += 256) gh[(size_t)i * nblk + b] = h[i];
}

__global__ __launch_bounds__(64)
void part_scan1_kernel(int* __restrict__ gh, int* __restrict__ btot, int nblk) {
    int k = blockIdx.x;
    int t = threadIdx.x;
    int* row = gh + (size_t)k * nblk;
    int chunk = (nblk + 63) >> 6;
    int lo = t * chunk, hi = min(lo + chunk, nblk);
    int s = 0;
    for (int i = lo; i < hi; ++i) s += row[i];
    int incl = s;
#pragma unroll
    for (int d2 = 1; d2 < 64; d2 <<= 1) { int u = __shfl_up(incl, d2, 64); if (t >= d2) incl += u; }
    int excl = incl - s;
    for (int i = lo; i < hi; ++i) { int c = row[i]; row[i] = excl; excl += c; }
    if (t == 63) btot[k] = incl;
}

__global__ __launch_bounds__(1024)
void part_scan2_kernel(const int* __restrict__ btot, int* __restrict__ bbase,
                       int nb, int* __restrict__ offN) {
    __shared__ int ws[16];
    int t = threadIdx.x, lane = t & 63, wid = t >> 6;
    int v = (t < nb) ? btot[t] : 0;
    int incl = v;
#pragma unroll
    for (int d2 = 1; d2 < 64; d2 <<= 1) { int u = __shfl_up(incl, d2, 64); if (lane >= d2) incl += u; }
    if (lane == 63) ws[wid] = incl;
    __syncthreads();
    if (wid == 0) {
        int w = (lane < 16) ? ws[lane] : 0;
#pragma unroll
        for (int d2 = 1; d2 < 16; d2 <<= 1) { int u = __shfl_up(w, d2, 64); if (lane >= d2) w += u; }
        if (lane < 16) ws[lane] = w;
    }
    __syncthreads();
    int base = wid ? ws[wid - 1] : 0;
    int excl = base + incl - v;
    if (t < nb) bbase[t] = excl;
    if (t == nb - 1) { bbase[nb] = excl + v; *offN = excl + v; }
}

// record = (dst_local << 16) | src   (src < 65536)
__global__ __launch_bounds__(256)
void part_scatter_kernel(const int* __restrict__ src, const int* __restrict__ dst,
                         const int* __restrict__ gh, const int* __restrict__ bbase,
                         u32* __restrict__ ebuf, int E, int nb, int nblk) {
    __shared__ int cur[NB_MAX];
    int b = blockIdx.x;
    for (int i = threadIdx.x; i < nb; i += 256)
        cur[i] = bbase[i] + gh[(size_t)i * nblk + b];
    __syncthreads();
    int lo = b * CHUNK, hi = min(lo + CHUNK, E);
    for (int i = lo + threadIdx.x; i < hi; i += 256) {
        int d = dst[i];
        int p = atomicAdd(&cur[d >> BW_LOG], 1);
        ebuf[p] = ((u32)(d & (BWID - 1)) << 16) | (u32)src[i];
    }
}

__global__ __launch_bounds__(256)
void bucket_sort_kernel(u32* __restrict__ ebuf, const int* __restrict__ bbase,
                        int* __restrict__ off, int n_nodes) {
    __shared__ u32 in_s[CAP];
    __shared__ u16 out_s[CAP];
    __shared__ int hist[BWID], cur[BWID];
    int b = blockIdx.x;
    int base = bbase[b];
    int n_b = bbase[b + 1] - base;
    int t = threadIdx.x;
    if (t < BWID) hist[t] = 0;
    for (int i = t; i < n_b && i < CAP; i += 256) in_s[i] = ebuf[base + i];
    __syncthreads();
    for (int i = t; i < n_b && i < CAP; i += 256) atomicAdd(&hist[in_s[i] >> 16], 1);
    __syncthreads();
    if (t < BWID) {
        int s = hist[t];
        int incl = s;
#pragma unroll
        for (int d2 = 1; d2 < 64; d2 <<= 1) { int u = __shfl_up(incl, d2, 64); if (t >= d2) incl += u; }
        int excl = incl - s;
        cur[t] = excl;
        int node = (b << BW_LOG) + t;
        if (node < n_nodes) off[node] = base + excl;
    }
    __syncthreads();
    for (int i = t; i < n_b && i < CAP; i += 256) {
        u32 v = in_s[i];
        int p = atomicAdd(&cur[v >> 16], 1);
        if (p < CAP) out_s[p] = (u16)(v & 0xffffu);
    }
    __syncthreads();
    for (int i = t; i < n_b && i < CAP; i += 256) ebuf[base + i] = (u32)out_s[i];
}

// ---------- mean aggregation over bf16 rows ----------
// R5-measured best shape: 32 lanes/node (ushort4), 8 nodes/block, unroll x8.
// 16 random rows in flight per wave — measured sweet spot between latency hiding
// and L2 thrash (R8's 32-rows-in-flight variant: FETCH 147->213MB, 51->68us).

__global__ __launch_bounds__(256)
void aggregate_bf16_kernel(const u16* __restrict__ xb, const int* __restrict__ off,
                           const u32* __restrict__ eidx, u16* __restrict__ meanb,
                           int n_nodes) {
    int node = blockIdx.x * 8 + (threadIdx.x >> 5);
    int lane = threadIdx.x & 31;
    if (node >= n_nodes) return;
    int beg = off[node], end = off[node + 1];
    int c = lane * 4;

    float ax = 0.f, ay = 0.f, az = 0.f, aw = 0.f;
    int e = beg;
    for (; e + 8 <= end; e += 8) {
        ushort4 v0 = *(const ushort4*)&xb[(size_t)eidx[e + 0] * D + c];
        ushort4 v1 = *(const ushort4*)&xb[(size_t)eidx[e + 1] * D + c];
        ushort4 v2 = *(const ushort4*)&xb[(size_t)eidx[e + 2] * D + c];
        ushort4 v3 = *(const ushort4*)&xb[(size_t)eidx[e + 3] * D + c];
        ushort4 v4 = *(const ushort4*)&xb[(size_t)eidx[e + 4] * D + c];
        ushort4 v5 = *(const ushort4*)&xb[(size_t)eidx[e + 5] * D + c];
        ushort4 v6 = *(const ushort4*)&xb[(size_t)eidx[e + 6] * D + c];
        ushort4 v7 = *(const ushort4*)&xb[(size_t)eidx[e + 7] * D + c];
        ax += bf2f(v0.x) + bf2f(v1.x) + bf2f(v2.x) + bf2f(v3.x)
            + bf2f(v4.x) + bf2f(v5.x) + bf2f(v6.x) + bf2f(v7.x);
        ay += bf2f(v0.y) + bf2f(v1.y) + bf2f(v2.y) + bf2f(v3.y)
            + bf2f(v4.y) + bf2f(v5.y) + bf2f(v6.y) + bf2f(v7.y);
        az += bf2f(v0.z) + bf2f(v1.z) + bf2f(v2.z) + bf2f(v3.z)
            + bf2f(v4.z) + bf2f(v5.z) + bf2f(v6.z) + bf2f(v7.z);
        aw += bf2f(v0.w) + bf2f(v1.w) + bf2f(v2.w) + bf2f(v3.w)
            + bf2f(v4.w) + bf2f(v5.w) + bf2f(v6.w) + bf2f(v7.w);
    }
    for (; e < end; ++e) {
        ushort4 v = *(const ushort4*)&xb[(size_t)eidx[e] * D + c];
        ax += bf2f(v.x); ay += bf2f(v.y); az += bf2f(v.z); aw += bf2f(v.w);
    }

    int deg = end - beg;
    float inv = 1.f / (float)(deg > 0 ? deg : 1);
    ushort4 o;
    o.x = f2bf(ax * inv); o.y = f2bf(ay * inv); o.z = f2bf(az * inv); o.w = f2bf(aw * inv);
    *(ushort4*)&meanb[(size_t)node * D + c] = o;
}

// ---------- linear via MFMA with LDS-staged W ----------
// out = relu([mean||self] @ Wcat^T + b). Block = 64 rows (4 waves x 16-row tiles).
// Wcat (128x256 bf16) staged in LDS in two 32KB k-halves.
// mfma_f32_16x16x32_bf16: A row=l&15, k=(l>>4)*8+j ; C/D col=l&15, row=(l>>4)*4+reg.

template<bool OUT_BF16>
__global__ __launch_bounds__(256)
void linear_mfma_kernel(const u16* __restrict__ Amean, const u16* __restrict__ Aself,
                        const u16* __restrict__ Wc, const float* __restrict__ bias,
                        void* __restrict__ outp, int N) {
    __shared__ u16 ws[128][136];   // 34816 B

    int t = threadIdx.x;
    int l = t & 63;
    int wv = t >> 6;
    int m0 = blockIdx.x * 64 + wv * 16;
    int lr = l & 15;
    int kg = (l >> 4) * 8;
    int rowA = m0 + lr;
    int rc = rowA < N ? rowA : N - 1;
    const u16* r1 = Amean + (size_t)rc * D;
    const u16* r2 = Aself + (size_t)rc * D;

    bf16x8 a[8];
#pragma unroll
    for (int kt = 0; kt < 4; ++kt) {
        a[kt]     = *(const bf16x8*)(r1 + kt * 32 + kg);   // k 0..127  (mean)
        a[kt + 4] = *(const bf16x8*)(r2 + kt * 32 + kg);   // k 128..255 (self)
    }

    f32x4 acc[8];
#pragma unroll
    for (int nt = 0; nt < 8; ++nt) acc[nt] = (f32x4){0.f, 0.f, 0.f, 0.f};

    for (int half = 0; half < 2; ++half) {
        if (half) __syncthreads();         // all reads of previous half done
        // stage 128x128 bf16 k-half of Wcat: 2048 x 16B, 8 per thread
        for (int i = t; i < 2048; i += 256) {
            int n = i >> 4, kq = i & 15;
            *(u16x8*)&ws[n][kq * 8] = *(const u16x8*)&Wc[(size_t)n * 256 + half * 128 + kq * 8];
        }
        __syncthreads();

#pragma unroll
        for (int nt = 0; nt < 8; ++nt) {
            bf16x8 b0 = *(const bf16x8*)&ws[nt * 16 + lr][0 * 32 + kg];
            bf16x8 b1 = *(const bf16x8*)&ws[nt * 16 + lr][1 * 32 + kg];
            bf16x8 b2 = *(const bf16x8*)&ws[nt * 16 + lr][2 * 32 + kg];
            bf16x8 b3 = *(const bf16x8*)&ws[nt * 16 + lr][3 * 32 + kg];
            acc[nt] = __builtin_amdgcn_mfma_f32_16x16x32_bf16(a[half * 4 + 0], b0, acc[nt], 0, 0, 0);
            acc[nt] = __builtin_amdgcn_mfma_f32_16x16x32_bf16(a[half * 4 + 1], b1, acc[nt], 0, 0, 0);
            acc[nt] = __builtin_amdgcn_mfma_f32_16x16x32_bf16(a[half * 4 + 2], b2, acc[nt], 0, 0, 0);
            acc[nt] = __builtin_amdgcn_mfma_f32_16x16x32_bf16(a[half * 4 + 3], b3, acc[nt], 0, 0, 0);
        }
    }

#pragma unroll
    for (int nt = 0; nt < 8; ++nt) {
        int col = nt * 16 + lr;
        float bb = bias[col];
#pragma unroll
        for (int j = 0; j < 4; ++j) {
            int r = m0 + (l >> 4) * 4 + j;
            if (r < N) {
                float v = fmaxf(acc[nt][j] + bb, 0.f);
                if (OUT_BF16) ((u16*)outp)[(size_t)r * D + col] = f2bf(v);
                else          ((float*)outp)[(size_t)r * D + col] = v;
            }
        }
    }
}

extern "C" void kernel_launch(void* const* d_in, const int* in_sizes, int n_in,
                              void* d_out, int out_size, void* d_ws, size_t ws_size,
                              hipStream_t stream) {
    const float* x   = (const float*)d_in[0];
    const int*   ei  = (const int*)d_in[1];
    const float* W1l = (const float*)d_in[2];
    const float* W1r = (const float*)d_in[3];
    const float* b1  = (const float*)d_in[4];
    const float* W2l = (const float*)d_in[5];
    const float* W2r = (const float*)d_in[6];
    const float* b2  = (const float*)d_in[7];
    float* out = (float*)d_out;

    const int N = in_sizes[0] / D;
    const int E = in_sizes[1] / 2;
    const int* src = ei;
    const int* dst = ei + E;
    const int NB = (N + BWID - 1) >> BW_LOG;       // 782 for N=50000 (<= NB_MAX)
    const int NBLK = (E + CHUNK - 1) / CHUNK;      // 391 for E=1.6M

    // workspace layout, 64B-aligned blocks
    char* wp_ = (char*)d_ws;
    auto alloc = [&](size_t bytes) { char* p = wp_; wp_ += (bytes + 63) & ~(size_t)63; return p; };
    int* off_p   = (int*)alloc((size_t)(N + 1) * 4);
    int* bbase_p = (int*)alloc((size_t)(NB + 1) * 4);
    int* btot_p  = (int*)alloc((size_t)NB * 4);
    int* gh_p    = (int*)alloc((size_t)NB * NBLK * 4);
    u32* ebuf_p  = (u32*)alloc((size_t)E * 4);
    u16* xb      = (u16*)alloc((size_t)N * D * 2);
    u16* meanb   = (u16*)alloc((size_t)N * D * 2);
    u16* h1b     = (u16*)alloc((size_t)N * D * 2);
    u16* wc1     = (u16*)alloc((size_t)128 * 256 * 2);
    u16* wc2     = (u16*)alloc((size_t)128 * 256 * 2);

    // conversions
    cvt_x_kernel<<<(N * D / 4 + 255) / 256, 256, 0, stream>>>(x, xb, N * D / 4);
    cvt_w_kernel<<<256, 256, 0, stream>>>(W1l, W1r, W2l, W2r, wc1, wc2);

    // CSR build
    part_hist_kernel<<<NBLK, 256, 0, stream>>>(dst, gh_p, E, NB, NBLK);
    part_scan1_kernel<<<NB, 64, 0, stream>>>(gh_p, btot_p, NBLK);
    part_scan2_kernel<<<1, 1024, 0, stream>>>(btot_p, bbase_p, NB, off_p + N);
    part_scatter_kernel<<<NBLK, 256, 0, stream>>>(src, dst, gh_p, bbase_p, ebuf_p, E, NB, NBLK);
    bucket_sort_kernel<<<NB, 256, 0, stream>>>(ebuf_p, bbase_p, off_p, N);

    // layer 1
    aggregate_bf16_kernel<<<(N + 7) / 8, 256, 0, stream>>>(xb, off_p, ebuf_p, meanb, N);
    linear_mfma_kernel<true><<<(N + 63) / 64, 256, 0, stream>>>(meanb, xb, wc1, b1, h1b, N);

    // layer 2
    aggregate_bf16_kernel<<<(N + 7) / 8, 256, 0, stream>>>(h1b, off_p, ebuf_p, meanb, N);
    linear_mfma_kernel<false><<<(N + 63) / 64, 256, 0, stream>>>(meanb, h1b, wc2, b2, out, N);
}